// Round 1
// baseline (1069.218 us; speedup 1.0000x reference)
//
#include <hip/hip_runtime.h>

typedef short v8s __attribute__((ext_vector_type(8)));
typedef float v4f __attribute__((ext_vector_type(4)));
typedef unsigned short u16;

#define BM 128
#define BN 128
#define BK 64

__device__ __forceinline__ u16 f2bf(float f) {
  union { float f; unsigned int u; } v; v.f = f;
  unsigned int r = (v.u + 0x7FFFu + ((v.u >> 16) & 1u)) >> 16;
  return (u16)r;
}
__device__ __forceinline__ float bf2f(u16 b) {
  union { unsigned int u; float f; } v; v.u = ((unsigned int)b) << 16;
  return v.f;
}

__device__ __forceinline__ void gld16(const void* g, void* l) {
  __builtin_amdgcn_global_load_lds(
      (const __attribute__((address_space(1))) void*)g,
      (__attribute__((address_space(3))) void*)l, 16, 0, 0);
}

// ---------------- conversions / packing ----------------

__global__ void cvt_f32_bf16_x8(const float* __restrict__ in, u16* __restrict__ out, long n8) {
  const long i = (long)blockIdx.x * 256 + threadIdx.x;
  if (i >= n8) return;
  const float4 x = ((const float4*)in)[i * 2];
  const float4 y = ((const float4*)in)[i * 2 + 1];
  v8s o;
  o[0] = (short)f2bf(x.x); o[1] = (short)f2bf(x.y);
  o[2] = (short)f2bf(x.z); o[3] = (short)f2bf(x.w);
  o[4] = (short)f2bf(y.x); o[5] = (short)f2bf(y.y);
  o[6] = (short)f2bf(y.z); o[7] = (short)f2bf(y.w);
  ((v8s*)out)[i] = o;
}

// W1 f32 [6][512][256] -> W1t bf16 [5*256][512]  (rows = s*256+n, cols = k)
__global__ void packW1(const float* __restrict__ W1, u16* __restrict__ W1t) {
  const int idx = blockIdx.x * 256 + threadIdx.x;   // 5*256*512
  const int k = idx & 511, sn = idx >> 9;
  const int s = sn >> 8, n = sn & 255;
  W1t[idx] = f2bf(W1[((long)(1 + s) * 512 + k) * 256 + n]);
}

// W2 f32 [6][256][128] -> W2t bf16 [5*128][256]
__global__ void packW2(const float* __restrict__ W2, u16* __restrict__ W2t) {
  const int idx = blockIdx.x * 256 + threadIdx.x;   // 5*128*256
  const int k = idx & 255, sn = idx >> 8;
  const int s = sn >> 7, n = sn & 127;
  W2t[idx] = f2bf(W2[((long)(1 + s) * 256 + k) * 128 + n]);
}

// ---------------- generic bf16 gemm_bt: C = op(A @ B^T) ----------------
// A: [M][K] row-major bf16 (lda), B: [N][K] row-major bf16 (ldb)
// MODE 0: C[m][n] = relu(..)  bf16 row-major (ldc)
// MODE 1: C[n][m] = ..        bf16 transposed store (ldc = M-stride)

template <int MODE>
__global__ __launch_bounds__(256, 3) void gemm_bt(
    const u16* __restrict__ A, long lda, long zA,
    const u16* __restrict__ B, long ldb, long zB,
    u16* __restrict__ C, long ldc, long zC, int K) {
  __shared__ u16 As[BM * BK];
  __shared__ u16 Bs[BN * BK];
  const int tid = threadIdx.x;
  const long m0 = (long)blockIdx.y * BM;
  const long n0 = (long)blockIdx.x * BN;
  const u16* Ap = A + (long)blockIdx.z * zA;
  const u16* Bp = B + (long)blockIdx.z * zB;

  const int wave = tid >> 6, lane = tid & 63;
  const int wr = wave >> 1, wc = wave & 1;
  const int lq = lane >> 4, lr = lane & 15;

  v4f acc[4][4] = {};

  for (int k0 = 0; k0 < K; k0 += BK) {
    __syncthreads();
#pragma unroll
    for (int i = 0; i < 4; ++i) {
      const int c = i * 256 + tid;
      const int row = c >> 3, j = c & 7;
      const int kc = j ^ (row & 7);                 // XOR bank swizzle
      gld16(Ap + (m0 + row) * lda + (k0 + kc * 8), &As[c * 8]);
      gld16(Bp + (n0 + row) * ldb + (k0 + kc * 8), &Bs[c * 8]);
    }
    __syncthreads();
#pragma unroll
    for (int kk = 0; kk < 2; ++kk) {
      v8s a[4], b[4];
#pragma unroll
      for (int mi = 0; mi < 4; ++mi) {
        const int m = wr * 64 + mi * 16 + lr;
        const int ch = m * 8 + ((kk * 4 + lq) ^ (m & 7));
        a[mi] = *(const v8s*)&As[ch * 8];
      }
#pragma unroll
      for (int ni = 0; ni < 4; ++ni) {
        const int n = wc * 64 + ni * 16 + lr;
        const int ch = n * 8 + ((kk * 4 + lq) ^ (n & 7));
        b[ni] = *(const v8s*)&Bs[ch * 8];
      }
#pragma unroll
      for (int mi = 0; mi < 4; ++mi)
#pragma unroll
        for (int ni = 0; ni < 4; ++ni)
          acc[mi][ni] = __builtin_amdgcn_mfma_f32_16x16x32_bf16(a[mi], b[ni], acc[mi][ni], 0, 0, 0);
    }
  }

  if (MODE == 0) {
    u16* Cp = C + (long)blockIdx.z * zC;
#pragma unroll
    for (int mi = 0; mi < 4; ++mi) {
      const long mb = m0 + wr * 64 + mi * 16 + lq * 4;
#pragma unroll
      for (int ni = 0; ni < 4; ++ni) {
        const long n = n0 + wc * 64 + ni * 16 + lr;
#pragma unroll
        for (int r = 0; r < 4; ++r) {
          float v = acc[mi][ni][r];
          v = v > 0.f ? v : 0.f;                    // relu
          Cp[(mb + r) * ldc + n] = f2bf(v);
        }
      }
    }
  } else {
    u16* Cp = C + (long)blockIdx.z * zC;
#pragma unroll
    for (int ni = 0; ni < 4; ++ni) {
      const long n = n0 + wc * 64 + ni * 16 + lr;
#pragma unroll
      for (int mi = 0; mi < 4; ++mi) {
        const long mb = m0 + wr * 64 + mi * 16 + lq * 4;
        ushort4 pk;
        pk.x = f2bf(acc[mi][ni][0]);
        pk.y = f2bf(acc[mi][ni][1]);
        pk.z = f2bf(acc[mi][ni][2]);
        pk.w = f2bf(acc[mi][ni][3]);
        *(ushort4*)&Cp[n * ldc + mb] = pk;          // transposed store
      }
    }
  }
}

// ---------------- column mean over Acat [8192][640] ----------------

__global__ void colsum(const u16* __restrict__ H, float* __restrict__ sums) {
  const int c = blockIdx.x * 64 + (threadIdx.x & 63);
  const int rt = threadIdx.x >> 6;
  const int r0 = blockIdx.y * 256;
  float s = 0.f;
  for (int r = r0 + rt; r < r0 + 256; r += 4) s += bf2f(H[(long)r * 640 + c]);
  __shared__ float red[256];
  red[threadIdx.x] = s;
  __syncthreads();
  if (threadIdx.x < 64) {
    float t = red[threadIdx.x] + red[threadIdx.x + 64] + red[threadIdx.x + 128] + red[threadIdx.x + 192];
    atomicAdd(&sums[c], t);
  }
}

__global__ void subme(u16* __restrict__ H, const float* __restrict__ sums) {
  const long i = (long)blockIdx.x * 256 + threadIdx.x;   // 8192*640
  const int c = (int)(i % 640);
  H[i] = f2bf(bf2f(H[i]) - sums[c] * (1.0f / 8192.0f));
}

// ---------------- G5: out = sum_s c_s * sigmoid(A_s @ A_s^T) / denom ----------------

__global__ __launch_bounds__(256, 2) void g5_kernel(
    const u16* __restrict__ Acat,                   // [8192][640]
    const float* __restrict__ som,                  // sqrt_omac
    const float* __restrict__ cum,                  // cum_sqrt
    float* __restrict__ out) {
  __shared__ u16 As[BM * BK];
  __shared__ u16 Bs[BN * BK];
  const int tid = threadIdx.x;
  const long m0 = (long)blockIdx.y * BM;
  const long n0 = (long)blockIdx.x * BN;
  const int wave = tid >> 6, lane = tid & 63;
  const int wr = wave >> 1, wc = wave & 1;
  const int lq = lane >> 4, lr = lane & 15;
  const float invden = 1.0f / cum[0];

  v4f oacc[4][4] = {};
  for (int s = 0; s < 5; ++s) {
    const float cs = som[s];
    v4f acc[4][4] = {};
    for (int t = 0; t < 2; ++t) {
      const int k0 = s * 128 + t * 64;
      __syncthreads();
#pragma unroll
      for (int i = 0; i < 4; ++i) {
        const int c = i * 256 + tid;
        const int row = c >> 3, j = c & 7;
        const int kc = j ^ (row & 7);
        gld16(Acat + (m0 + row) * 640 + (k0 + kc * 8), &As[c * 8]);
        gld16(Acat + (n0 + row) * 640 + (k0 + kc * 8), &Bs[c * 8]);
      }
      __syncthreads();
#pragma unroll
      for (int kk = 0; kk < 2; ++kk) {
        v8s a[4], b[4];
#pragma unroll
        for (int mi = 0; mi < 4; ++mi) {
          const int m = wr * 64 + mi * 16 + lr;
          const int ch = m * 8 + ((kk * 4 + lq) ^ (m & 7));
          a[mi] = *(const v8s*)&As[ch * 8];
        }
#pragma unroll
        for (int ni = 0; ni < 4; ++ni) {
          const int n = wc * 64 + ni * 16 + lr;
          const int ch = n * 8 + ((kk * 4 + lq) ^ (n & 7));
          b[ni] = *(const v8s*)&Bs[ch * 8];
        }
#pragma unroll
        for (int mi = 0; mi < 4; ++mi)
#pragma unroll
          for (int ni = 0; ni < 4; ++ni)
            acc[mi][ni] = __builtin_amdgcn_mfma_f32_16x16x32_bf16(a[mi], b[ni], acc[mi][ni], 0, 0, 0);
      }
    }
#pragma unroll
    for (int mi = 0; mi < 4; ++mi)
#pragma unroll
      for (int ni = 0; ni < 4; ++ni)
#pragma unroll
        for (int r = 0; r < 4; ++r) {
          const float z = acc[mi][ni][r];
          oacc[mi][ni][r] += cs / (1.0f + __expf(-z));
        }
  }
#pragma unroll
  for (int mi = 0; mi < 4; ++mi) {
    const long mb = m0 + wr * 64 + mi * 16 + lq * 4;
#pragma unroll
    for (int ni = 0; ni < 4; ++ni) {
      const long n = n0 + wc * 64 + ni * 16 + lr;
#pragma unroll
      for (int r = 0; r < 4; ++r)
        out[(mb + r) * 8192 + n] = oacc[mi][ni][r] * invden;
    }
  }
}

// ---------------- host ----------------

extern "C" void kernel_launch(void* const* d_in, const int* in_sizes, int n_in,
                              void* d_out, int out_size, void* d_ws, size_t ws_size,
                              hipStream_t stream) {
  const float* X   = (const float*)d_in[0];
  const float* adj = (const float*)d_in[1];
  const float* W1  = (const float*)d_in[2];
  const float* W2  = (const float*)d_in[3];
  const float* cum = (const float*)d_in[4];
  const float* som = (const float*)d_in[5];

  // Big scratch lives inside d_out (256 MB, fully overwritten by g5 at the end).
  char* ob = (char*)d_out;
  u16* adjb = (u16*)(ob);                       // 8192*8192 bf16 = 128 MB
  u16* T1t  = (u16*)(ob + 134217728);           // [1280][8192] bf16 = 20 MB
  u16* H1   = (u16*)(ob + 155189248);           // [8192][1280] bf16 = 20 MB
  u16* T2t  = (u16*)(ob + 176160768);           // [640][8192]  bf16 = 10 MB
  u16* Xb   = (u16*)(ob + 186646528);           // [8192][512]  bf16 = 8 MB

  // Small scratch in d_ws (~12.2 MB needed). Acat must survive into g5 (which writes d_out).
  char* wb = (char*)d_ws;
  u16* W1t   = (u16*)(wb);                      // [1280][512] bf16
  u16* W2t   = (u16*)(wb + 1310720);            // [640][256]  bf16
  u16* Acat  = (u16*)(wb + 1638400);            // [8192][640] bf16 (H2 then centered A)
  float* sums = (float*)(wb + 12124160);        // 640 f32

  cvt_f32_bf16_x8<<<32768, 256, 0, stream>>>(adj, adjb, 8388608);
  cvt_f32_bf16_x8<<<2048, 256, 0, stream>>>(X, Xb, 524288);
  packW1<<<2560, 256, 0, stream>>>(W1, W1t);
  packW2<<<640, 256, 0, stream>>>(W2, W2t);

  // G1: T1t[n][m] = (Xb @ W1t^T), K=512, N=1280
  gemm_bt<1><<<dim3(10, 64, 1), 256, 0, stream>>>(Xb, 512, 0, W1t, 512, 0, T1t, 8192, 0, 512);
  // G2: H1[m][n] = relu(adjb @ T1t^T), K=8192, N=1280
  gemm_bt<0><<<dim3(10, 64, 1), 256, 0, stream>>>(adjb, 8192, 0, T1t, 8192, 0, H1, 1280, 0, 8192);
  // G3 (batched over s): T2t[s*128+n][m] = H1_s @ W2t_s^T, K=256
  gemm_bt<1><<<dim3(1, 64, 5), 256, 0, stream>>>(H1, 1280, 256, W2t, 256, 128 * 256, T2t, 8192, (long)128 * 8192, 256);
  // G4: Acat[m][n] = relu(adjb @ T2t^T), K=8192, N=640  (raw H2, bf16)
  gemm_bt<0><<<dim3(5, 64, 1), 256, 0, stream>>>(adjb, 8192, 0, T2t, 8192, 0, Acat, 640, 0, 8192);

  hipMemsetAsync(sums, 0, 640 * sizeof(float), stream);
  colsum<<<dim3(10, 32), 256, 0, stream>>>(Acat, sums);
  subme<<<20480, 256, 0, stream>>>(Acat, sums);

  // G5: out = sum_s c_s*sigmoid(A_s A_s^T)/denom, writes all of d_out
  g5_kernel<<<dim3(64, 64), 256, 0, stream>>>(Acat, som, cum, (float*)d_out);
}

// Round 2
// 1038.078 us; speedup vs baseline: 1.0300x; 1.0300x over previous
//
#include <hip/hip_runtime.h>

typedef short v8s __attribute__((ext_vector_type(8)));
typedef float v4f __attribute__((ext_vector_type(4)));
typedef unsigned short u16;

#define BM 128
#define BN 128
#define BK 64
#define LP 132   // padded f32 leading dim for transpose tile

__device__ __forceinline__ u16 f2bf(float f) {
  union { float f; unsigned int u; } v; v.f = f;
  unsigned int r = (v.u + 0x7FFFu + ((v.u >> 16) & 1u)) >> 16;
  return (u16)r;
}
__device__ __forceinline__ float bf2f(u16 b) {
  union { unsigned int u; float f; } v; v.u = ((unsigned int)b) << 16;
  return v.f;
}

__device__ __forceinline__ void gld16(const void* g, void* l) {
  __builtin_amdgcn_global_load_lds(
      (const __attribute__((address_space(1))) void*)g,
      (__attribute__((address_space(3))) void*)l, 16, 0, 0);
}

// ---------------- conversions / packing ----------------

__global__ void cvt_f32_bf16_x8(const float* __restrict__ in, u16* __restrict__ out, long n8) {
  const long i = (long)blockIdx.x * 256 + threadIdx.x;
  if (i >= n8) return;
  const float4 x = ((const float4*)in)[i * 2];
  const float4 y = ((const float4*)in)[i * 2 + 1];
  v8s o;
  o[0] = (short)f2bf(x.x); o[1] = (short)f2bf(x.y);
  o[2] = (short)f2bf(x.z); o[3] = (short)f2bf(x.w);
  o[4] = (short)f2bf(y.x); o[5] = (short)f2bf(y.y);
  o[6] = (short)f2bf(y.z); o[7] = (short)f2bf(y.w);
  ((v8s*)out)[i] = o;
}

// W1 f32 [6][512][256] -> W1t bf16 [5*256][512]  (rows = s*256+n, cols = k)
__global__ void packW1(const float* __restrict__ W1, u16* __restrict__ W1t) {
  const int idx = blockIdx.x * 256 + threadIdx.x;   // 5*256*512
  const int k = idx & 511, sn = idx >> 9;
  const int s = sn >> 8, n = sn & 255;
  W1t[idx] = f2bf(W1[((long)(1 + s) * 512 + k) * 256 + n]);
}

// W2 f32 [6][256][128] -> W2t bf16 [5*128][256]
__global__ void packW2(const float* __restrict__ W2, u16* __restrict__ W2t) {
  const int idx = blockIdx.x * 256 + threadIdx.x;   // 5*128*256
  const int k = idx & 255, sn = idx >> 8;
  const int s = sn >> 7, n = sn & 127;
  W2t[idx] = f2bf(W2[((long)(1 + s) * 256 + k) * 128 + n]);
}

// ---------------- generic bf16 gemm_bt: C = op(A @ B^T) ----------------

template <int MODE>
__global__ __launch_bounds__(256, 3) void gemm_bt(
    const u16* __restrict__ A, long lda, long zA,
    const u16* __restrict__ B, long ldb, long zB,
    u16* __restrict__ C, long ldc, long zC, int K) {
  __shared__ u16 As[BM * BK];
  __shared__ u16 Bs[BN * BK];
  const int tid = threadIdx.x;
  const long m0 = (long)blockIdx.y * BM;
  const long n0 = (long)blockIdx.x * BN;
  const u16* Ap = A + (long)blockIdx.z * zA;
  const u16* Bp = B + (long)blockIdx.z * zB;

  const int wave = tid >> 6, lane = tid & 63;
  const int wr = wave >> 1, wc = wave & 1;
  const int lq = lane >> 4, lr = lane & 15;

  v4f acc[4][4] = {};

  for (int k0 = 0; k0 < K; k0 += BK) {
    __syncthreads();
#pragma unroll
    for (int i = 0; i < 4; ++i) {
      const int c = i * 256 + tid;
      const int row = c >> 3, j = c & 7;
      const int kc = j ^ (row & 7);                 // XOR bank swizzle
      gld16(Ap + (m0 + row) * lda + (k0 + kc * 8), &As[c * 8]);
      gld16(Bp + (n0 + row) * ldb + (k0 + kc * 8), &Bs[c * 8]);
    }
    __syncthreads();
#pragma unroll
    for (int kk = 0; kk < 2; ++kk) {
      v8s a[4], b[4];
#pragma unroll
      for (int mi = 0; mi < 4; ++mi) {
        const int m = wr * 64 + mi * 16 + lr;
        const int ch = m * 8 + ((kk * 4 + lq) ^ (m & 7));
        a[mi] = *(const v8s*)&As[ch * 8];
      }
#pragma unroll
      for (int ni = 0; ni < 4; ++ni) {
        const int n = wc * 64 + ni * 16 + lr;
        const int ch = n * 8 + ((kk * 4 + lq) ^ (n & 7));
        b[ni] = *(const v8s*)&Bs[ch * 8];
      }
#pragma unroll
      for (int mi = 0; mi < 4; ++mi)
#pragma unroll
        for (int ni = 0; ni < 4; ++ni)
          acc[mi][ni] = __builtin_amdgcn_mfma_f32_16x16x32_bf16(a[mi], b[ni], acc[mi][ni], 0, 0, 0);
    }
  }

  if (MODE == 0) {
    u16* Cp = C + (long)blockIdx.z * zC;
#pragma unroll
    for (int mi = 0; mi < 4; ++mi) {
      const long mb = m0 + wr * 64 + mi * 16 + lq * 4;
#pragma unroll
      for (int ni = 0; ni < 4; ++ni) {
        const long n = n0 + wc * 64 + ni * 16 + lr;
#pragma unroll
        for (int r = 0; r < 4; ++r) {
          float v = acc[mi][ni][r];
          v = v > 0.f ? v : 0.f;                    // relu
          Cp[(mb + r) * ldc + n] = f2bf(v);
        }
      }
    }
  } else {
    u16* Cp = C + (long)blockIdx.z * zC;
#pragma unroll
    for (int ni = 0; ni < 4; ++ni) {
      const long n = n0 + wc * 64 + ni * 16 + lr;
#pragma unroll
      for (int mi = 0; mi < 4; ++mi) {
        const long mb = m0 + wr * 64 + mi * 16 + lq * 4;
        ushort4 pk;
        pk.x = f2bf(acc[mi][ni][0]);
        pk.y = f2bf(acc[mi][ni][1]);
        pk.z = f2bf(acc[mi][ni][2]);
        pk.w = f2bf(acc[mi][ni][3]);
        *(ushort4*)&Cp[n * ldc + mb] = pk;          // transposed store
      }
    }
  }
}

// ---------------- column mean over Acat [8192][640] ----------------

__global__ void colsum(const u16* __restrict__ H, float* __restrict__ sums) {
  const int c = blockIdx.x * 64 + (threadIdx.x & 63);
  const int rt = threadIdx.x >> 6;
  const int r0 = blockIdx.y * 256;
  float s = 0.f;
  for (int r = r0 + rt; r < r0 + 256; r += 4) s += bf2f(H[(long)r * 640 + c]);
  __shared__ float red[256];
  red[threadIdx.x] = s;
  __syncthreads();
  if (threadIdx.x < 64) {
    float t = red[threadIdx.x] + red[threadIdx.x + 64] + red[threadIdx.x + 128] + red[threadIdx.x + 192];
    atomicAdd(&sums[c], t);
  }
}

__global__ void subme(u16* __restrict__ H, const float* __restrict__ sums) {
  const long i = (long)blockIdx.x * 256 + threadIdx.x;   // 8192*640
  const int c = (int)(i % 640);
  H[i] = f2bf(bf2f(H[i]) - sums[c] * (1.0f / 8192.0f));
}

// ---------------- G5: out = sum_s c_s * sigmoid(A_s @ A_s^T) / denom ----------------
// Symmetric: only upper-triangle blocks (bx >= by) compute; each writes its
// tile and (if bx > by) the mirrored tile via an LDS transpose.

__global__ __launch_bounds__(256, 2) void g5_kernel(
    const u16* __restrict__ Acat,                   // [8192][640]
    const float* __restrict__ som,                  // sqrt_omac
    const float* __restrict__ cum,                  // cum_sqrt
    float* __restrict__ out) {
  const int bx = blockIdx.x, by = blockIdx.y;
  if (by > bx) return;                              // symmetry: skip lower triangle

  __shared__ __align__(16) char smem[34048];        // staging (32KB) / transpose (33792B) overlay
  u16* As = (u16*)smem;
  u16* Bs = As + BM * BK;
  float* Lf = (float*)smem;                         // [64][LP]

  const int tid = threadIdx.x;
  const long m0 = (long)by * BM;
  const long n0 = (long)bx * BN;
  const int wave = tid >> 6, lane = tid & 63;
  const int wr = wave >> 1, wc = wave & 1;
  const int lq = lane >> 4, lr = lane & 15;
  const float invden = 1.0f / cum[0];
  const float NL2E = -1.4426950408889634f;

  v4f oacc[4][4] = {};
  for (int s = 0; s < 5; ++s) {
    const float cs = som[s];
    v4f acc[4][4] = {};
    for (int t = 0; t < 2; ++t) {
      const int k0 = s * 128 + t * 64;
      __syncthreads();
#pragma unroll
      for (int i = 0; i < 4; ++i) {
        const int c = i * 256 + tid;
        const int row = c >> 3, j = c & 7;
        const int kc = j ^ (row & 7);
        gld16(Acat + (m0 + row) * 640 + (k0 + kc * 8), &As[c * 8]);
        gld16(Acat + (n0 + row) * 640 + (k0 + kc * 8), &Bs[c * 8]);
      }
      __syncthreads();
#pragma unroll
      for (int kk = 0; kk < 2; ++kk) {
        v8s a[4], b[4];
#pragma unroll
        for (int mi = 0; mi < 4; ++mi) {
          const int m = wr * 64 + mi * 16 + lr;
          const int ch = m * 8 + ((kk * 4 + lq) ^ (m & 7));
          a[mi] = *(const v8s*)&As[ch * 8];
        }
#pragma unroll
        for (int ni = 0; ni < 4; ++ni) {
          const int n = wc * 64 + ni * 16 + lr;
          const int ch = n * 8 + ((kk * 4 + lq) ^ (n & 7));
          b[ni] = *(const v8s*)&Bs[ch * 8];
        }
#pragma unroll
        for (int mi = 0; mi < 4; ++mi)
#pragma unroll
          for (int ni = 0; ni < 4; ++ni)
            acc[mi][ni] = __builtin_amdgcn_mfma_f32_16x16x32_bf16(a[mi], b[ni], acc[mi][ni], 0, 0, 0);
      }
    }
    // fast sigmoid: cs * rcp(1 + 2^(-z*log2(e)))
#pragma unroll
    for (int mi = 0; mi < 4; ++mi)
#pragma unroll
      for (int ni = 0; ni < 4; ++ni)
#pragma unroll
        for (int r = 0; r < 4; ++r) {
          const float z = acc[mi][ni][r];
          const float e = __builtin_amdgcn_exp2f(z * NL2E);
          oacc[mi][ni][r] += cs * __builtin_amdgcn_rcpf(1.0f + e);
        }
  }

  // epilogue: two 64-row halves through LDS; coalesced float4 stores
  const bool mirror = (bx > by);
#pragma unroll
  for (int h = 0; h < 2; ++h) {
    __syncthreads();                                // Lf overlays As/Bs (and prev half)
    if (wr == h) {
#pragma unroll
      for (int mi = 0; mi < 4; ++mi)
#pragma unroll
        for (int ni = 0; ni < 4; ++ni) {
          const int lcol = wc * 64 + ni * 16 + lr;
#pragma unroll
          for (int r = 0; r < 4; ++r) {
            const int lrow = mi * 16 + lq * 4 + r;
            Lf[lrow * LP + lcol] = oacc[mi][ni][r] * invden;
          }
        }
    }
    __syncthreads();
    // direct tile: rows m0+h*64+row, cols n0..n0+127
    {
      const int row = tid >> 2;                     // 0..63
      const int cb = (tid & 3) * 32;
      float* op = out + (m0 + h * 64 + row) * 8192L + n0 + cb;
      const float* lp = &Lf[row * LP + cb];
#pragma unroll
      for (int i = 0; i < 8; ++i)
        ((float4*)op)[i] = *(const float4*)(lp + i * 4);
    }
    // mirrored tile: rows n0+c, cols m0+h*64..+63
    if (mirror) {
#pragma unroll
      for (int p = 0; p < 2; ++p) {
        const int c = p * 64 + (tid >> 2);          // 0..127 (orig col)
        const int rb = (tid & 3) * 16;              // orig row chunk
        float4 v0, v1, v2, v3;
        float t0[16];
#pragma unroll
        for (int j = 0; j < 16; ++j) t0[j] = Lf[(rb + j) * LP + c];
        v0 = make_float4(t0[0], t0[1], t0[2], t0[3]);
        v1 = make_float4(t0[4], t0[5], t0[6], t0[7]);
        v2 = make_float4(t0[8], t0[9], t0[10], t0[11]);
        v3 = make_float4(t0[12], t0[13], t0[14], t0[15]);
        float* op = out + (n0 + c) * 8192L + m0 + h * 64 + rb;
        ((float4*)op)[0] = v0;
        ((float4*)op)[1] = v1;
        ((float4*)op)[2] = v2;
        ((float4*)op)[3] = v3;
      }
    }
  }
}

// ---------------- host ----------------

extern "C" void kernel_launch(void* const* d_in, const int* in_sizes, int n_in,
                              void* d_out, int out_size, void* d_ws, size_t ws_size,
                              hipStream_t stream) {
  const float* X   = (const float*)d_in[0];
  const float* adj = (const float*)d_in[1];
  const float* W1  = (const float*)d_in[2];
  const float* W2  = (const float*)d_in[3];
  const float* cum = (const float*)d_in[4];
  const float* som = (const float*)d_in[5];

  // Big scratch lives inside d_out (256 MB, fully overwritten by g5 at the end).
  char* ob = (char*)d_out;
  u16* adjb = (u16*)(ob);                       // 8192*8192 bf16 = 128 MB
  u16* T1t  = (u16*)(ob + 134217728);           // [1280][8192] bf16 = 20 MB
  u16* H1   = (u16*)(ob + 155189248);           // [8192][1280] bf16 = 20 MB
  u16* T2t  = (u16*)(ob + 176160768);           // [640][8192]  bf16 = 10 MB
  u16* Xb   = (u16*)(ob + 186646528);           // [8192][512]  bf16 = 8 MB

  // Small scratch in d_ws (~12.2 MB needed). Acat must survive into g5 (which writes d_out).
  char* wb = (char*)d_ws;
  u16* W1t   = (u16*)(wb);                      // [1280][512] bf16
  u16* W2t   = (u16*)(wb + 1310720);            // [640][256]  bf16
  u16* Acat  = (u16*)(wb + 1638400);            // [8192][640] bf16 (H2 then centered A)
  float* sums = (float*)(wb + 12124160);        // 640 f32

  cvt_f32_bf16_x8<<<32768, 256, 0, stream>>>(adj, adjb, 8388608);
  cvt_f32_bf16_x8<<<2048, 256, 0, stream>>>(X, Xb, 524288);
  packW1<<<2560, 256, 0, stream>>>(W1, W1t);
  packW2<<<640, 256, 0, stream>>>(W2, W2t);

  // G1: T1t[n][m] = (Xb @ W1t^T), K=512, N=1280
  gemm_bt<1><<<dim3(10, 64, 1), 256, 0, stream>>>(Xb, 512, 0, W1t, 512, 0, T1t, 8192, 0, 512);
  // G2: H1[m][n] = relu(adjb @ T1t^T), K=8192, N=1280
  gemm_bt<0><<<dim3(10, 64, 1), 256, 0, stream>>>(adjb, 8192, 0, T1t, 8192, 0, H1, 1280, 0, 8192);
  // G3 (batched over s): T2t[s*128+n][m] = H1_s @ W2t_s^T, K=256
  gemm_bt<1><<<dim3(1, 64, 5), 256, 0, stream>>>(H1, 1280, 256, W2t, 256, 128 * 256, T2t, 8192, (long)128 * 8192, 256);
  // G4: Acat[m][n] = relu(adjb @ T2t^T), K=8192, N=640  (raw H2, bf16)
  gemm_bt<0><<<dim3(5, 64, 1), 256, 0, stream>>>(adjb, 8192, 0, T2t, 8192, 0, Acat, 640, 0, 8192);

  hipMemsetAsync(sums, 0, 640 * sizeof(float), stream);
  colsum<<<dim3(10, 32), 256, 0, stream>>>(Acat, sums);
  subme<<<20480, 256, 0, stream>>>(Acat, sums);

  // G5: out = sum_s c_s*sigmoid(A_s A_s^T)/denom, writes all of d_out
  g5_kernel<<<dim3(64, 64), 256, 0, stream>>>(Acat, som, cum, (float*)d_out);
}

// Round 3
// 821.656 us; speedup vs baseline: 1.3013x; 1.2634x over previous
//
#include <hip/hip_runtime.h>

typedef short v8s __attribute__((ext_vector_type(8)));
typedef float v4f __attribute__((ext_vector_type(4)));
typedef int   v4i __attribute__((ext_vector_type(4)));
typedef int   v8i __attribute__((ext_vector_type(8)));
typedef unsigned short u16;
typedef unsigned char  u8;

#define BM 128
#define BN 128
#define BK 64
#define LP 132   // padded f32 leading dim for transpose tile

// e8m0 scale bytes (value = 2^(x-127)), broadcast to all 4 bytes
#define SCALE_M13 0x72727272   // 2^-13
#define SCALE_0   0x7F7F7F7F   // 2^0
#define SCALE_M6  0x79797979   // 2^-6
#define SCALE_M12 0x73737373   // 2^-12

__device__ __forceinline__ u16 f2bf(float f) {
  union { float f; unsigned int u; } v; v.f = f;
  unsigned int r = (v.u + 0x7FFFu + ((v.u >> 16) & 1u)) >> 16;
  return (u16)r;
}
__device__ __forceinline__ float bf2f(u16 b) {
  union { unsigned int u; float f; } v; v.u = ((unsigned int)b) << 16;
  return v.f;
}
__device__ __forceinline__ unsigned int pk4fp8(float a, float b, float c, float d) {
  unsigned int p = __builtin_amdgcn_cvt_pk_fp8_f32(a, b, 0, false);
  p = __builtin_amdgcn_cvt_pk_fp8_f32(c, d, p, true);
  return p;
}

__device__ __forceinline__ void gld16(const void* g, void* l) {
  __builtin_amdgcn_global_load_lds(
      (const __attribute__((address_space(1))) void*)g,
      (__attribute__((address_space(3))) void*)l, 16, 0, 0);
}

// fp8 fragment load: 32 contiguous K-bytes (global chunks 2q,2q+1) from
// XOR-swizzled LDS tile (rows of 128B, 16B slot j holds global chunk j^(row&7))
__device__ __forceinline__ v8i ldfrag8(const u8* S, int m, int q) {
  const int s0 = (2 * q) ^ (m & 7);
  const v4i lo = *(const v4i*)(S + m * 128 + s0 * 16);
  const v4i hi = *(const v4i*)(S + m * 128 + (s0 ^ 1) * 16);
  v8i r;
  r[0] = lo[0]; r[1] = lo[1]; r[2] = lo[2]; r[3] = lo[3];
  r[4] = hi[0]; r[5] = hi[1]; r[6] = hi[2]; r[7] = hi[3];
  return r;
}

// ---------------- conversions / packing ----------------

__global__ void cvt_f32_bf16_x8(const float* __restrict__ in, u16* __restrict__ out, long n8) {
  const long i = (long)blockIdx.x * 256 + threadIdx.x;
  if (i >= n8) return;
  const float4 x = ((const float4*)in)[i * 2];
  const float4 y = ((const float4*)in)[i * 2 + 1];
  v8s o;
  o[0] = (short)f2bf(x.x); o[1] = (short)f2bf(x.y);
  o[2] = (short)f2bf(x.z); o[3] = (short)f2bf(x.w);
  o[4] = (short)f2bf(y.x); o[5] = (short)f2bf(y.y);
  o[6] = (short)f2bf(y.z); o[7] = (short)f2bf(y.w);
  ((v8s*)out)[i] = o;
}

__global__ void cvt_f32_fp8_x8(const float* __restrict__ in, u8* __restrict__ out,
                               float scale, long n8) {
  const long i = (long)blockIdx.x * 256 + threadIdx.x;
  if (i >= n8) return;
  const float4 x = ((const float4*)in)[i * 2];
  const float4 y = ((const float4*)in)[i * 2 + 1];
  uint2 p;
  p.x = pk4fp8(x.x * scale, x.y * scale, x.z * scale, x.w * scale);
  p.y = pk4fp8(y.x * scale, y.y * scale, y.z * scale, y.w * scale);
  ((uint2*)out)[i] = p;
}

// W1 f32 [6][512][256] -> W1t bf16 [5*256][512]
__global__ void packW1(const float* __restrict__ W1, u16* __restrict__ W1t) {
  const int idx = blockIdx.x * 256 + threadIdx.x;
  const int k = idx & 511, sn = idx >> 9;
  const int s = sn >> 8, n = sn & 255;
  W1t[idx] = f2bf(W1[((long)(1 + s) * 512 + k) * 256 + n]);
}

// W2 f32 [6][256][128] -> W2t bf16 [5*128][256]
__global__ void packW2(const float* __restrict__ W2, u16* __restrict__ W2t) {
  const int idx = blockIdx.x * 256 + threadIdx.x;
  const int k = idx & 255, sn = idx >> 8;
  const int s = sn >> 7, n = sn & 127;
  W2t[idx] = f2bf(W2[((long)(1 + s) * 256 + k) * 128 + n]);
}

// ---------------- bf16 gemm_bt, fp8-transposed output ----------------
// C8[n][m] = fp8( (A@B^T)[m][n] * oscale )

__global__ __launch_bounds__(256, 3) void gemm_bt_o8(
    const u16* __restrict__ A, long lda, long zA,
    const u16* __restrict__ B, long ldb, long zB,
    u8* __restrict__ C, long ldc, long zC, int K, float oscale) {
  __shared__ u16 As[BM * BK];
  __shared__ u16 Bs[BN * BK];
  const int tid = threadIdx.x;
  const long m0 = (long)blockIdx.y * BM;
  const long n0 = (long)blockIdx.x * BN;
  const u16* Ap = A + (long)blockIdx.z * zA;
  const u16* Bp = B + (long)blockIdx.z * zB;

  const int wave = tid >> 6, lane = tid & 63;
  const int wr = wave >> 1, wc = wave & 1;
  const int lq = lane >> 4, lr = lane & 15;

  v4f acc[4][4] = {};

  for (int k0 = 0; k0 < K; k0 += BK) {
    __syncthreads();
#pragma unroll
    for (int i = 0; i < 4; ++i) {
      const int c = i * 256 + tid;
      const int row = c >> 3, j = c & 7;
      const int kc = j ^ (row & 7);
      gld16(Ap + (m0 + row) * lda + (k0 + kc * 8), &As[c * 8]);
      gld16(Bp + (n0 + row) * ldb + (k0 + kc * 8), &Bs[c * 8]);
    }
    __syncthreads();
#pragma unroll
    for (int kk = 0; kk < 2; ++kk) {
      v8s a[4], b[4];
#pragma unroll
      for (int mi = 0; mi < 4; ++mi) {
        const int m = wr * 64 + mi * 16 + lr;
        const int ch = m * 8 + ((kk * 4 + lq) ^ (m & 7));
        a[mi] = *(const v8s*)&As[ch * 8];
      }
#pragma unroll
      for (int ni = 0; ni < 4; ++ni) {
        const int n = wc * 64 + ni * 16 + lr;
        const int ch = n * 8 + ((kk * 4 + lq) ^ (n & 7));
        b[ni] = *(const v8s*)&Bs[ch * 8];
      }
#pragma unroll
      for (int mi = 0; mi < 4; ++mi)
#pragma unroll
        for (int ni = 0; ni < 4; ++ni)
          acc[mi][ni] = __builtin_amdgcn_mfma_f32_16x16x32_bf16(a[mi], b[ni], acc[mi][ni], 0, 0, 0);
    }
  }

  u8* Cp = C + (long)blockIdx.z * zC;
#pragma unroll
  for (int ni = 0; ni < 4; ++ni) {
    const long n = n0 + wc * 64 + ni * 16 + lr;
#pragma unroll
    for (int mi = 0; mi < 4; ++mi) {
      const long mb = m0 + wr * 64 + mi * 16 + lq * 4;
      const unsigned int p = pk4fp8(acc[mi][ni][0] * oscale, acc[mi][ni][1] * oscale,
                                    acc[mi][ni][2] * oscale, acc[mi][ni][3] * oscale);
      *(unsigned int*)&Cp[n * ldc + mb] = p;
    }
  }
}

// ---------------- MX-fp8 gemm_bt: C_bf16 = relu(scale_a*A @ (scale_b*B)^T) ----------------
// A: [M][K] fp8 (lda), B: [N][K] fp8 (ldb), BK=128, mfma 16x16x128

__global__ __launch_bounds__(256, 3) void gemm_fp8(
    const u8* __restrict__ A, long lda,
    const u8* __restrict__ B, long ldb,
    u16* __restrict__ C, long ldc, int K, int sa, int sb) {
  __shared__ u8 As[128 * 128];
  __shared__ u8 Bs[128 * 128];
  const int tid = threadIdx.x;
  const long m0 = (long)blockIdx.y * 128;
  const long n0 = (long)blockIdx.x * 128;
  const int wave = tid >> 6, lane = tid & 63;
  const int wr = wave >> 1, wc = wave & 1;
  const int lq = lane >> 4, lr = lane & 15;

  v4f acc[4][4] = {};

  for (int k0 = 0; k0 < K; k0 += 128) {
    __syncthreads();
#pragma unroll
    for (int i = 0; i < 4; ++i) {
      const int c = i * 256 + tid;
      const int row = c >> 3, j = c & 7;
      const int kc = j ^ (row & 7);
      gld16(A + (m0 + row) * lda + (k0 + kc * 16), &As[c * 16]);
      gld16(B + (n0 + row) * ldb + (k0 + kc * 16), &Bs[c * 16]);
    }
    __syncthreads();
    v8i a[4];
#pragma unroll
    for (int mi = 0; mi < 4; ++mi)
      a[mi] = ldfrag8(As, wr * 64 + mi * 16 + lr, lq);
#pragma unroll
    for (int ni = 0; ni < 4; ++ni) {
      const v8i b = ldfrag8(Bs, wc * 64 + ni * 16 + lr, lq);
#pragma unroll
      for (int mi = 0; mi < 4; ++mi)
        acc[mi][ni] = __builtin_amdgcn_mfma_scale_f32_16x16x128_f8f6f4(
            a[mi], b, acc[mi][ni], 0, 0, 0, sa, 0, sb);
    }
  }

#pragma unroll
  for (int mi = 0; mi < 4; ++mi) {
    const long mb = m0 + wr * 64 + mi * 16 + lq * 4;
#pragma unroll
    for (int ni = 0; ni < 4; ++ni) {
      const long n = n0 + wc * 64 + ni * 16 + lr;
#pragma unroll
      for (int r = 0; r < 4; ++r) {
        float v = acc[mi][ni][r];
        v = v > 0.f ? v : 0.f;                      // relu
        C[(mb + r) * ldc + n] = f2bf(v);
      }
    }
  }
}

// ---------------- column mean over Acat bf16 [8192][640] ----------------

__global__ void colsum(const u16* __restrict__ H, float* __restrict__ sums) {
  const int c = blockIdx.x * 64 + (threadIdx.x & 63);
  const int rt = threadIdx.x >> 6;
  const int r0 = blockIdx.y * 256;
  float s = 0.f;
  for (int r = r0 + rt; r < r0 + 256; r += 4) s += bf2f(H[(long)r * 640 + c]);
  __shared__ float red[256];
  red[threadIdx.x] = s;
  __syncthreads();
  if (threadIdx.x < 64) {
    float t = red[threadIdx.x] + red[threadIdx.x + 64] + red[threadIdx.x + 128] + red[threadIdx.x + 192];
    atomicAdd(&sums[c], t);
  }
}

// subtract mean, scale by 2^12, store fp8
__global__ void subme(const u16* __restrict__ H, const float* __restrict__ sums,
                      u8* __restrict__ O) {
  const long i4 = ((long)blockIdx.x * 256 + threadIdx.x) * 4;   // 8192*640 total
  const int c = (int)(i4 % 640);
  const float inv = 1.0f / 8192.0f;
  const float a0 = (bf2f(H[i4 + 0]) - sums[c + 0] * inv) * 4096.0f;
  const float a1 = (bf2f(H[i4 + 1]) - sums[c + 1] * inv) * 4096.0f;
  const float a2 = (bf2f(H[i4 + 2]) - sums[c + 2] * inv) * 4096.0f;
  const float a3 = (bf2f(H[i4 + 3]) - sums[c + 3] * inv) * 4096.0f;
  *(unsigned int*)&O[i4] = pk4fp8(a0, a1, a2, a3);
}

// ---------------- G5: out = sum_s c_s * sigmoid(A_s @ A_s^T) / denom ----------------
// fp8 MX (A pre-scaled 2^12), symmetric: upper-triangle blocks write both tiles.

__global__ __launch_bounds__(256, 2) void g5_fp8(
    const u8* __restrict__ A8,                      // [8192][640] fp8 = a*2^12
    const float* __restrict__ som,
    const float* __restrict__ cum,
    float* __restrict__ out) {
  const int bx = blockIdx.x, by = blockIdx.y;
  if (by > bx) return;

  __shared__ __align__(16) char smem[34048];        // 32KB staging / 33792B transpose overlay
  u8* As = (u8*)smem;
  u8* Bs = As + 16384;
  float* Lf = (float*)smem;                         // [64][LP]

  const int tid = threadIdx.x;
  const long m0 = (long)by * BM;
  const long n0 = (long)bx * BN;
  const int wave = tid >> 6, lane = tid & 63;
  const int wr = wave >> 1, wc = wave & 1;
  const int lq = lane >> 4, lr = lane & 15;
  const float invden = 1.0f / cum[0];
  const float NL2E = -1.4426950408889634f;

  v4f oacc[4][4] = {};
  for (int s = 0; s < 5; ++s) {
    const float cs = som[s];
    __syncthreads();
#pragma unroll
    for (int i = 0; i < 4; ++i) {
      const int c = i * 256 + tid;
      const int row = c >> 3, j = c & 7;
      const int kc = j ^ (row & 7);
      gld16(A8 + (m0 + row) * 640 + (s * 128 + kc * 16), &As[c * 16]);
      gld16(A8 + (n0 + row) * 640 + (s * 128 + kc * 16), &Bs[c * 16]);
    }
    __syncthreads();
    v8i a[4];
#pragma unroll
    for (int mi = 0; mi < 4; ++mi)
      a[mi] = ldfrag8(As, wr * 64 + mi * 16 + lr, lq);
    v4f acc[4][4] = {};
#pragma unroll
    for (int ni = 0; ni < 4; ++ni) {
      const v8i b = ldfrag8(Bs, wc * 64 + ni * 16 + lr, lq);
#pragma unroll
      for (int mi = 0; mi < 4; ++mi)
        acc[mi][ni] = __builtin_amdgcn_mfma_scale_f32_16x16x128_f8f6f4(
            a[mi], b, acc[mi][ni], 0, 0, 0, SCALE_M12, 0, SCALE_M12);
    }
#pragma unroll
    for (int mi = 0; mi < 4; ++mi)
#pragma unroll
      for (int ni = 0; ni < 4; ++ni)
#pragma unroll
        for (int r = 0; r < 4; ++r) {
          const float z = acc[mi][ni][r];
          const float e = __builtin_amdgcn_exp2f(z * NL2E);
          oacc[mi][ni][r] += cs * __builtin_amdgcn_rcpf(1.0f + e);
        }
  }

  const bool mirror = (bx > by);
#pragma unroll
  for (int h = 0; h < 2; ++h) {
    __syncthreads();
    if (wr == h) {
#pragma unroll
      for (int mi = 0; mi < 4; ++mi)
#pragma unroll
        for (int ni = 0; ni < 4; ++ni) {
          const int lcol = wc * 64 + ni * 16 + lr;
#pragma unroll
          for (int r = 0; r < 4; ++r) {
            const int lrow = mi * 16 + lq * 4 + r;
            Lf[lrow * LP + lcol] = oacc[mi][ni][r] * invden;
          }
        }
    }
    __syncthreads();
    {
      const int row = tid >> 2;
      const int cb = (tid & 3) * 32;
      float* op = out + (m0 + h * 64 + row) * 8192L + n0 + cb;
      const float* lp = &Lf[row * LP + cb];
#pragma unroll
      for (int i = 0; i < 8; ++i)
        ((float4*)op)[i] = *(const float4*)(lp + i * 4);
    }
    if (mirror) {
#pragma unroll
      for (int p = 0; p < 2; ++p) {
        const int c = p * 64 + (tid >> 2);
        const int rb = (tid & 3) * 16;
        float t0[16];
#pragma unroll
        for (int j = 0; j < 16; ++j) t0[j] = Lf[(rb + j) * LP + c];
        float* op = out + (n0 + c) * 8192L + m0 + h * 64 + rb;
        ((float4*)op)[0] = make_float4(t0[0], t0[1], t0[2], t0[3]);
        ((float4*)op)[1] = make_float4(t0[4], t0[5], t0[6], t0[7]);
        ((float4*)op)[2] = make_float4(t0[8], t0[9], t0[10], t0[11]);
        ((float4*)op)[3] = make_float4(t0[12], t0[13], t0[14], t0[15]);
      }
    }
  }
}

// ---------------- host ----------------

extern "C" void kernel_launch(void* const* d_in, const int* in_sizes, int n_in,
                              void* d_out, int out_size, void* d_ws, size_t ws_size,
                              hipStream_t stream) {
  const float* X   = (const float*)d_in[0];
  const float* adj = (const float*)d_in[1];
  const float* W1  = (const float*)d_in[2];
  const float* W2  = (const float*)d_in[3];
  const float* cum = (const float*)d_in[4];
  const float* som = (const float*)d_in[5];

  // Big scratch inside d_out (256 MB, fully overwritten by g5 at the end).
  char* ob = (char*)d_out;
  u8*  adjb8 = (u8*)(ob);                       // [8192][8192] fp8 (adj*2^13)  64 MB
  u8*  T1t8  = (u8*)(ob + 67108864);            // [1280][8192] fp8 (t1*2^0)    10 MB
  u16* H1    = (u16*)(ob + 77594624);           // [8192][1280] bf16            20 MB
  u8*  T2t8  = (u8*)(ob + 98566144);            // [640][8192]  fp8 (t2*2^6)     5 MB
  u16* Xb    = (u16*)(ob + 103809024);          // [8192][512]  bf16             8 MB
  u16* Acat  = (u16*)(ob + 112197632);          // [8192][640]  bf16 (raw h2)   10 MB

  // d_ws: Acat8 must survive into g5 (which writes d_out).
  char* wb = (char*)d_ws;
  u16* W1t   = (u16*)(wb);                      // [1280][512] bf16   1.31 MB
  u16* W2t   = (u16*)(wb + 1310720);            // [640][256]  bf16   0.33 MB
  u8*  Acat8 = (u8*)(wb + 1638400);             // [8192][640] fp8 (a*2^12) 5.24 MB
  float* sums = (float*)(wb + 6881280);         // 640 f32

  cvt_f32_fp8_x8<<<32768, 256, 0, stream>>>(adj, adjb8, 8192.0f, 8388608);  // *2^13
  cvt_f32_bf16_x8<<<2048, 256, 0, stream>>>(X, Xb, 524288);
  packW1<<<2560, 256, 0, stream>>>(W1, W1t);
  packW2<<<640, 256, 0, stream>>>(W2, W2t);

  // G1 (bf16): T1t8[n][m] = fp8(Xb @ W1t^T), K=512
  gemm_bt_o8<<<dim3(10, 64, 1), 256, 0, stream>>>(Xb, 512, 0, W1t, 512, 0,
                                                  T1t8, 8192, 0, 512, 1.0f);
  // G2 (MX-fp8): H1 = relu(2^-13*adjb8 @ T1t8^T), K=8192
  gemm_fp8<<<dim3(10, 64), 256, 0, stream>>>(adjb8, 8192, T1t8, 8192,
                                             H1, 1280, 8192, SCALE_M13, SCALE_0);
  // G3 (bf16, batched s): T2t8[s*128+n][m] = fp8(64 * H1_s @ W2t_s^T), K=256
  gemm_bt_o8<<<dim3(1, 64, 5), 256, 0, stream>>>(H1, 1280, 256, W2t, 256, 128 * 256,
                                                 T2t8, 8192, (long)128 * 8192, 256, 64.0f);
  // G4 (MX-fp8): Acat = relu(2^-13*adjb8 @ (2^-6*T2t8)^T), K=8192
  gemm_fp8<<<dim3(5, 64), 256, 0, stream>>>(adjb8, 8192, T2t8, 8192,
                                            Acat, 640, 8192, SCALE_M13, SCALE_M6);

  hipMemsetAsync(sums, 0, 640 * sizeof(float), stream);
  colsum<<<dim3(10, 32), 256, 0, stream>>>(Acat, sums);
  subme<<<5120, 256, 0, stream>>>(Acat, sums, Acat8);

  // G5 (MX-fp8, symmetric): out = sum_s c_s*sigmoid(A_s A_s^T)/denom
  g5_fp8<<<dim3(64, 64), 256, 0, stream>>>(Acat8, som, cum, (float*)d_out);
}